// Round 7
// baseline (5737.112 us; speedup 1.0000x reference)
//
#include <hip/hip_runtime.h>

// ---------------- problem dims ----------------
#define TT   512
#define DIN  1024
#define DH   2048
#define DOUT 1024

// ---------------- launch shape ----------------
#define NWG   256    // WGs 0..127: h1 chain (+epilogue); 128..255: h2 chain
#define HALF  128
#define NTHR  512    // 8 waves; each wave owns 2 h-rows of its chain
#define NSLOT (TT + 1)
#define QSLOT (DH / 2)   // u64 words per slot (1024)

typedef unsigned int u32;
typedef unsigned long long u64;

// Records: u32 = f32 bits of h; SENT (NaN pattern) = empty; tanh output can
// never be NaN -> data IS the readiness flag (one-RT observe, no fences).
// Slot-per-step -> no ABA. Sentinel re-init per run (8.4 MB).
//
// ROUND-6 CHANGE — WAVE-BATCHED POLLING (request-count cut at constant
// bytes/hops). Evidence: R1==R4 (bytes halved, time identical) kills the
// byte model; R2 (+1 hop = +0.8us/step) and R3 (2x requests = +1.8us/step)
// point at L3 request-queueing inflating the hop latency. All prior configs
// had every one of the 131K threads polling -> ~786K tiny sc1 requests per
// retry round hammering 128 lines. Now ONE wave stages a whole 8KB slot:
// lane l owns a 128B window, 16 straight-line ld64 issues + single drain
// (batched-wait pattern proven in R5's poll), per-lane pending at 128B
// granularity. Waves 1..7 park at the barrier (zero retry traffic).
// Requests/round: h1 2048->1024, h2 4096->2048 per WG; device ~3x cut.
// Publish: per-wave immediate (R5's aggregation cost +0.46us/step —
// reverted), single u64 pair-store (both rows in one packet).
#define SENT  0xFFFFFFFFu
#define SENT2 0xFFFFFFFFFFFFFFFFull
__device__ u64 gR1[NSLOT * QSLOT];   // h1 records (u64-pair view)
__device__ u64 gR2[NSLOT * QSLOT];   // h2 records

__device__ __forceinline__ float dot4(float4 a, float4 b) {
  return a.x * b.x + a.y * b.y + a.z * b.z + a.w * b.w;
}
__device__ __forceinline__ float wave_sum(float v) {
  #pragma unroll
  for (int off = 32; off > 0; off >>= 1) v += __shfl_down(v, off, 64);
  return v; // lane 0 holds the sum
}
__device__ __forceinline__ u64 ld64(const u64* p) {
  return __hip_atomic_load((u64*)p, __ATOMIC_RELAXED, __HIP_MEMORY_SCOPE_AGENT);
}
__device__ __forceinline__ void st64(u64* p, u64 v) {
  __hip_atomic_store(p, v, __ATOMIC_RELAXED, __HIP_MEMORY_SCOPE_AGENT);
}
// both halves present? (bitwise & avoids short-circuit re-serialization)
__device__ __forceinline__ bool ok2(u64 q) {
  return ((u32)q != SENT) & ((u32)(q >> 32) != SENT);
}
// Fast tanh, ~3 ulp: lane 0 only, 2x per wave per step. Output always
// finite/non-NaN -> can never alias SENT.
__device__ __forceinline__ float fast_tanh(float x) {
  float xc = fminf(fmaxf(x, -9.0f), 9.0f);
  float e  = __expf(2.0f * xc);
  return (e - 1.0f) * __frcp_rn(e + 1.0f);
}

// One wave stages one 8KB slot. Lane l owns u64 words [16l, 16l+16)
// (= 128B). Per round: 16 back-to-back ld64 issues, ONE drain, then checks
// (sched_barrier keeps checks behind the whole issue burst). Per-lane
// pending: done lanes exit (exec-masked) and stop generating traffic.
__device__ __forceinline__ void wave_poll_stage(const u64* slot, float* lds,
                                                int l) {
  const u64* p = slot + 16 * (size_t)l;
  u64 q[16];
  #pragma unroll
  for (int k = 0; k < 16; ++k) q[k] = ld64(p + k);
  __builtin_amdgcn_sched_barrier(0);
  bool d = true;
  #pragma unroll
  for (int k = 0; k < 16; ++k) d &= ok2(q[k]);
  while (!d) {
    __builtin_amdgcn_s_sleep(1);
    #pragma unroll
    for (int k = 0; k < 16; ++k) q[k] = ld64(p + k);
    __builtin_amdgcn_sched_barrier(0);
    d = true;
    #pragma unroll
    for (int k = 0; k < 16; ++k) d &= ok2(q[k]);
  }
  float4* dst = (float4*)lds + 8 * l;
  #pragma unroll
  for (int k = 0; k < 8; ++k)
    dst[k] = make_float4(__uint_as_float((u32)q[2 * k]),
                         __uint_as_float((u32)(q[2 * k] >> 32)),
                         __uint_as_float((u32)q[2 * k + 1]),
                         __uint_as_float((u32)(q[2 * k + 1] >> 32)));
}

// Sentinel-fill all records before each run.
__global__ void init_kernel() {
  int i = blockIdx.x * blockDim.x + threadIdx.x;
  int n = gridDim.x * blockDim.x;
  for (int k = i; k < NSLOT * QSLOT; k += n) {
    st64(&gR1[k], SENT2);
    st64(&gR2[k], SENT2);
  }
}

__global__ __launch_bounds__(NTHR, 1)
void rnn2_kernel(const float* __restrict__ X,
                 const float* __restrict__ Wa, const float* __restrict__ ba,
                 const float* __restrict__ Wb, const float* __restrict__ bb,
                 const float* __restrict__ Wc, const float* __restrict__ bc,
                 const float* __restrict__ Wd, const float* __restrict__ bd,
                 const float* __restrict__ Wo, const float* __restrict__ bo,
                 float* __restrict__ out)
{
  const int g   = blockIdx.x;
  const int tid = threadIdx.x;
  const int w   = tid >> 6;   // wave
  const int l   = tid & 63;   // lane

  // Double-buffered staging; the one barrier per step between stage and dot
  // bounds wave skew -> parity-buffer reuse two steps later is race-free.
  __shared__ float sA[2][DH];
  __shared__ float sB[2][DH];

  if (g < HALF) {
    // ================= h1 chain (+ output epilogue) =================
    const int r0 = g * 16 + 2 * w, r1 = r0 + 1;   // my two h1 rows
    const int qidx = 8 * g + w;                   // their u64 word index
    float4 wA0[4], wA1[4], wB0[8], wB1[8], wO[8];
    {
      const float4* p0 = (const float4*)(Wa + (size_t)r0 * DIN);
      const float4* p1 = (const float4*)(Wa + (size_t)r1 * DIN);
      #pragma unroll
      for (int j = 0; j < 4; ++j) { wA0[j] = p0[l + 64 * j]; wA1[j] = p1[l + 64 * j]; }
    }
    {
      const float4* p0 = (const float4*)(Wb + (size_t)r0 * DH);
      const float4* p1 = (const float4*)(Wb + (size_t)r1 * DH);
      #pragma unroll
      for (int j = 0; j < 8; ++j) { wB0[j] = p0[l + 64 * j]; wB1[j] = p1[l + 64 * j]; }
    }
    const int orow = g * 8 + w;                   // my output row
    {
      const float4* p = (const float4*)(Wo + (size_t)orow * DH);
      #pragma unroll
      for (int j = 0; j < 8; ++j) wO[j] = p[l + 64 * j];
    }
    const float b1_0 = ba[r0] + bb[r0];
    const float b1_1 = ba[r1] + bb[r1];
    const float bo_r = bo[orow];

    for (int t = 1; t <= TT; ++t) {
      // wave 0: pre-issue poll round 0 for h1(t-1); drain is overlapped
      // with the X-dot below (compiler inserts the waitcnt at first use).
      const u64* pp = gR1 + (size_t)(t - 1) * QSLOT + 16 * (size_t)l;
      u64 q[16];
      if (w == 0 && t > 1) {
        #pragma unroll
        for (int k = 0; k < 16; ++k) q[k] = ld64(pp + k);
        __builtin_amdgcn_sched_barrier(0);
      }

      // A.x[t-1]: no cross-WG dependency — compute before the wait
      float a0 = 0.f, a1 = 0.f;
      {
        const float4* px = (const float4*)(X + (size_t)(t - 1) * DIN);
        #pragma unroll
        for (int j = 0; j < 4; ++j) {
          float4 x4 = px[l + 64 * j];
          a0 += dot4(wA0[j], x4);
          a1 += dot4(wA1[j], x4);
        }
      }

      if (t > 1) {
        float* buf = sA[(t - 1) & 1];
        if (w == 0) {   // finish the poll, stage to LDS
          bool d = true;
          #pragma unroll
          for (int k = 0; k < 16; ++k) d &= ok2(q[k]);
          while (!d) {
            __builtin_amdgcn_s_sleep(1);
            #pragma unroll
            for (int k = 0; k < 16; ++k) q[k] = ld64(pp + k);
            __builtin_amdgcn_sched_barrier(0);
            d = true;
            #pragma unroll
            for (int k = 0; k < 16; ++k) d &= ok2(q[k]);
          }
          float4* dst = (float4*)buf + 8 * l;
          #pragma unroll
          for (int k = 0; k < 8; ++k)
            dst[k] = make_float4(__uint_as_float((u32)q[2 * k]),
                                 __uint_as_float((u32)(q[2 * k] >> 32)),
                                 __uint_as_float((u32)q[2 * k + 1]),
                                 __uint_as_float((u32)(q[2 * k + 1] >> 32)));
        }
        __syncthreads();
        const float4* ph = (const float4*)buf;
        #pragma unroll
        for (int j = 0; j < 8; ++j) {
          float4 h4 = ph[l + 64 * j];
          a0 += dot4(wB0[j], h4);
          a1 += dot4(wB1[j], h4);
        }
      }
      a0 = wave_sum(a0); a1 = wave_sum(a1);
      if (l == 0) {   // publish both rows: ONE fire-and-forget u64 pair
        u64 pr = ((u64)__float_as_uint(fast_tanh(a1 + b1_1)) << 32)
               |  (u64)__float_as_uint(fast_tanh(a0 + b1_0));
        st64(gR1 + (size_t)t * QSLOT + qidx, pr);
      }
    }

    // ---- epilogue: out = Wo . h2[TT] + bo (1 row per wave) ----
    // sA[0] parity != the loop's last dot buffer (sA[1]) -> race-free.
    if (w == 0) wave_poll_stage(gR2 + (size_t)TT * QSLOT, sA[0], l);
    __syncthreads();
    {
      const float4* ph = (const float4*)sA[0];
      float acc = 0.f;
      #pragma unroll
      for (int j = 0; j < 8; ++j) acc += dot4(wO[j], ph[l + 64 * j]);
      acc = wave_sum(acc);
      if (l == 0) out[orow] = acc + bo_r;
    }
  } else {
    // ========================= h2 chain =========================
    const int gg = g - HALF;
    const int r0 = gg * 16 + 2 * w, r1 = r0 + 1;  // my two h2 rows
    const int qidx = 8 * gg + w;
    float4 wC0[8], wC1[8], wD0[8], wD1[8];
    {
      const float4* p0 = (const float4*)(Wc + (size_t)r0 * DH);
      const float4* p1 = (const float4*)(Wc + (size_t)r1 * DH);
      #pragma unroll
      for (int j = 0; j < 8; ++j) { wC0[j] = p0[l + 64 * j]; wC1[j] = p1[l + 64 * j]; }
    }
    {
      const float4* p0 = (const float4*)(Wd + (size_t)r0 * DH);
      const float4* p1 = (const float4*)(Wd + (size_t)r1 * DH);
      #pragma unroll
      for (int j = 0; j < 8; ++j) { wD0[j] = p0[l + 64 * j]; wD1[j] = p1[l + 64 * j]; }
    }
    const float b2_0 = bc[r0] + bd[r0];
    const float b2_1 = bc[r1] + bd[r1];

    for (int t = 1; t <= TT; ++t) {
      float* bufA = sA[t & 1];
      float* bufB = sB[t & 1];
      // Wave 0 stages h1(t); wave 1 stages h2(t-1) — in parallel.
      if (w == 0)
        wave_poll_stage(gR1 + (size_t)t * QSLOT, bufA, l);
      else if (w == 1 && t > 1)
        wave_poll_stage(gR2 + (size_t)(t - 1) * QSLOT, bufB, l);
      __syncthreads();

      float a0 = 0.f, a1 = 0.f;
      {
        const float4* ph = (const float4*)bufA;
        #pragma unroll
        for (int j = 0; j < 8; ++j) {
          float4 h4 = ph[l + 64 * j];
          a0 += dot4(wC0[j], h4);
          a1 += dot4(wC1[j], h4);
        }
      }
      if (t > 1) {
        const float4* ph = (const float4*)bufB;
        #pragma unroll
        for (int j = 0; j < 8; ++j) {
          float4 h4 = ph[l + 64 * j];
          a0 += dot4(wD0[j], h4);
          a1 += dot4(wD1[j], h4);
        }
      }
      a0 = wave_sum(a0); a1 = wave_sum(a1);
      if (l == 0) {
        u64 pr = ((u64)__float_as_uint(fast_tanh(a1 + b2_1)) << 32)
               |  (u64)__float_as_uint(fast_tanh(a0 + b2_0));
        st64(gR2 + (size_t)t * QSLOT + qidx, pr);
      }
    }
  }
}

extern "C" void kernel_launch(void* const* d_in, const int* in_sizes, int n_in,
                              void* d_out, int out_size, void* d_ws, size_t ws_size,
                              hipStream_t stream)
{
  (void)in_sizes; (void)n_in; (void)out_size; (void)d_ws; (void)ws_size;

  const float* X  = (const float*)d_in[0];
  const float* Wa = (const float*)d_in[1];   // W_i2h1 [H][IN]
  const float* ba = (const float*)d_in[2];
  const float* Wb = (const float*)d_in[3];   // W_h2h1 [H][H]
  const float* bb = (const float*)d_in[4];
  // d_in[5], d_in[6]: W_h2o1 / b_h2o1 — dead code in the reference
  const float* Wc = (const float*)d_in[7];   // W_i2h2 [H][H]
  const float* bc = (const float*)d_in[8];
  const float* Wd = (const float*)d_in[9];   // W_h2h2 [H][H]
  const float* bd = (const float*)d_in[10];
  const float* Wo = (const float*)d_in[11];  // W_h2o2 [OUT][H]
  const float* bo = (const float*)d_in[12];
  float* out = (float*)d_out;

  init_kernel<<<dim3(1024), dim3(256), 0, stream>>>();

  void* args[] = { &X, &Wa, &ba, &Wb, &bb, &Wc, &bc, &Wd, &bd, &Wo, &bo, &out };
  (void)hipLaunchCooperativeKernel((void*)rnn2_kernel, dim3(NWG), dim3(NTHR),
                                   args, 0, stream);
}

// Round 8
// 3002.895 us; speedup vs baseline: 1.9105x; 1.9105x over previous
//
#include <hip/hip_runtime.h>

// ---------------- problem dims ----------------
#define TT   512
#define DIN  1024
#define DH   2048
#define DOUT 1024

// ---------------- launch shape ----------------
#define NWG   256    // WGs 0..127: h1 chain (+epilogue); 128..255: h2 chain
#define HALF  128
#define NTHR  512    // 8 waves; each wave owns 2 h-rows of its chain
#define NSLOT (TT + 1)

typedef unsigned int u32;
typedef unsigned long long u64;

// ROUND-7: PHASE-SPLIT MEASUREMENT (correct-by-construction ablation).
// Base protocol = R4-best (1470us kernel): u32 sentinel records, guarded
// pending-only polls, immediate lane-0 publish. ONE structural change:
// h2 WGs quiet-gate on gR1[TT] (complete => every h1 producer finished all
// steps) before starting their loop, so phase 1 = h1 chain solo, phase 2 =
// h2 chain solo with h1 always-ready. Each phase has HALF the pollers and
// no cross-chain traffic. total/512 = P1+P2 decomposes the 2.86us joint
// period into intrinsic vs contention parts (contention ~ 2.86 - total/1024).
// h1 epilogue pre-gates on its first gR2[TT] record with slow sleep so its
// spin doesn't contaminate phase 2.
#define SENT 0xFFFFFFFFu
__device__ u32 gR1[NSLOT * DH];   // h1 records
__device__ u32 gR2[NSLOT * DH];   // h2 records

__device__ __forceinline__ float dot4(float4 a, float4 b) {
  return a.x * b.x + a.y * b.y + a.z * b.z + a.w * b.w;
}
__device__ __forceinline__ float wave_sum(float v) {
  #pragma unroll
  for (int off = 32; off > 0; off >>= 1) v += __shfl_down(v, off, 64);
  return v; // lane 0 holds the sum
}
__device__ __forceinline__ u32 ld_rec(const u32* p) {
  return __hip_atomic_load((u32*)p, __ATOMIC_RELAXED, __HIP_MEMORY_SCOPE_AGENT);
}
__device__ __forceinline__ void st_rec(u32* p, u32 v) {
  __hip_atomic_store(p, v, __ATOMIC_RELAXED, __HIP_MEMORY_SCOPE_AGENT);
}
// Fast tanh, ~3 ulp: lane 0 only, 2x per wave per step. Output always
// finite/non-NaN -> can never alias SENT.
__device__ __forceinline__ float fast_tanh(float x) {
  float xc = fminf(fmaxf(x, -9.0f), 9.0f);
  float e  = __expf(2.0f * xc);
  return (e - 1.0f) * __frcp_rn(e + 1.0f);
}

// R4-verbatim poll: pending-only guarded loads, sleep(1) retry.
__device__ __forceinline__ void poll_stage(const u32* rec, float* lds, int tid) {
  u32 v0 = SENT, v1 = SENT, v2 = SENT, v3 = SENT;
  bool d0 = false, d1 = false, d2 = false, d3 = false;
  for (;;) {
    if (!d0) { v0 = ld_rec(rec + tid           ); d0 = (v0 != SENT); }
    if (!d1) { v1 = ld_rec(rec + tid +     NTHR); d1 = (v1 != SENT); }
    if (!d2) { v2 = ld_rec(rec + tid + 2 * NTHR); d2 = (v2 != SENT); }
    if (!d3) { v3 = ld_rec(rec + tid + 3 * NTHR); d3 = (v3 != SENT); }
    if (d0 & d1 & d2 & d3) break;
    __builtin_amdgcn_s_sleep(1);
  }
  lds[tid           ] = __uint_as_float(v0);
  lds[tid +     NTHR] = __uint_as_float(v1);
  lds[tid + 2 * NTHR] = __uint_as_float(v2);
  lds[tid + 3 * NTHR] = __uint_as_float(v3);
}

// R4-verbatim dual-slot poll (h2: h1[t] and h2[t-1]). In phase 2 the A-slot
// (h1) hits on the first round; only the B-slot (own recurrence) ever waits.
__device__ __forceinline__ void poll_stage2(const u32* recA, const u32* recB,
                                            float* ldsA, float* ldsB, int tid) {
  u32 a0 = SENT, a1 = SENT, a2 = SENT, a3 = SENT;
  u32 b0 = SENT, b1 = SENT, b2 = SENT, b3 = SENT;
  bool da0 = false, da1 = false, da2 = false, da3 = false;
  bool db0 = false, db1 = false, db2 = false, db3 = false;
  for (;;) {
    if (!da0) { a0 = ld_rec(recA + tid           ); da0 = (a0 != SENT); }
    if (!da1) { a1 = ld_rec(recA + tid +     NTHR); da1 = (a1 != SENT); }
    if (!da2) { a2 = ld_rec(recA + tid + 2 * NTHR); da2 = (a2 != SENT); }
    if (!da3) { a3 = ld_rec(recA + tid + 3 * NTHR); da3 = (a3 != SENT); }
    if (!db0) { b0 = ld_rec(recB + tid           ); db0 = (b0 != SENT); }
    if (!db1) { b1 = ld_rec(recB + tid +     NTHR); db1 = (b1 != SENT); }
    if (!db2) { b2 = ld_rec(recB + tid + 2 * NTHR); db2 = (b2 != SENT); }
    if (!db3) { b3 = ld_rec(recB + tid + 3 * NTHR); db3 = (b3 != SENT); }
    if (da0 & da1 & da2 & da3 & db0 & db1 & db2 & db3) break;
    __builtin_amdgcn_s_sleep(1);
  }
  ldsA[tid           ] = __uint_as_float(a0);
  ldsA[tid +     NTHR] = __uint_as_float(a1);
  ldsA[tid + 2 * NTHR] = __uint_as_float(a2);
  ldsA[tid + 3 * NTHR] = __uint_as_float(a3);
  ldsB[tid           ] = __uint_as_float(b0);
  ldsB[tid +     NTHR] = __uint_as_float(b1);
  ldsB[tid + 2 * NTHR] = __uint_as_float(b2);
  ldsB[tid + 3 * NTHR] = __uint_as_float(b3);
}

// Quiet gate: guarded pending-only poll of one slot's 4 records per thread,
// with LONG sleep (64*64 = 4K clocks) so the waiting half of the device
// generates ~1/60 of a normal poll round's requests. Latency irrelevant.
__device__ __forceinline__ void quiet_gate(const u32* rec, int tid) {
  bool d0 = false, d1 = false, d2 = false, d3 = false;
  for (;;) {
    if (!d0) d0 = (ld_rec(rec + tid           ) != SENT);
    if (!d1) d1 = (ld_rec(rec + tid +     NTHR) != SENT);
    if (!d2) d2 = (ld_rec(rec + tid + 2 * NTHR) != SENT);
    if (!d3) d3 = (ld_rec(rec + tid + 3 * NTHR) != SENT);
    if (d0 & d1 & d2 & d3) break;
    __builtin_amdgcn_s_sleep(64);
  }
}

// Sentinel-fill all records before each run (agent-scope stores: must be
// visible to the main kernel's L2-bypassing poll loads).
__global__ void init_kernel() {
  int i = blockIdx.x * blockDim.x + threadIdx.x;
  int n = gridDim.x * blockDim.x;
  for (int k = i; k < NSLOT * DH; k += n) {
    st_rec(&gR1[k], SENT);
    st_rec(&gR2[k], SENT);
  }
}

__global__ __launch_bounds__(NTHR, 2)
void rnn2_kernel(const float* __restrict__ X,
                 const float* __restrict__ Wa, const float* __restrict__ ba,
                 const float* __restrict__ Wb, const float* __restrict__ bb,
                 const float* __restrict__ Wc, const float* __restrict__ bc,
                 const float* __restrict__ Wd, const float* __restrict__ bd,
                 const float* __restrict__ Wo, const float* __restrict__ bo,
                 float* __restrict__ out)
{
  const int g   = blockIdx.x;
  const int tid = threadIdx.x;
  const int w   = tid >> 6;   // wave
  const int l   = tid & 63;   // lane

  // Double-buffered staging; the one barrier per step between stage and dot
  // bounds wave skew -> parity-buffer reuse two steps later is race-free.
  __shared__ float sA[2][DH];
  __shared__ float sB[2][DH];

  if (g < HALF) {
    // ============ PHASE 1: h1 chain solo (+ output epilogue) ============
    const int r0 = g * 16 + 2 * w, r1 = r0 + 1;   // my two h1 rows
    float4 wA0[4], wA1[4], wB0[8], wB1[8], wO[8];
    {
      const float4* p0 = (const float4*)(Wa + (size_t)r0 * DIN);
      const float4* p1 = (const float4*)(Wa + (size_t)r1 * DIN);
      #pragma unroll
      for (int j = 0; j < 4; ++j) { wA0[j] = p0[l + 64 * j]; wA1[j] = p1[l + 64 * j]; }
    }
    {
      const float4* p0 = (const float4*)(Wb + (size_t)r0 * DH);
      const float4* p1 = (const float4*)(Wb + (size_t)r1 * DH);
      #pragma unroll
      for (int j = 0; j < 8; ++j) { wB0[j] = p0[l + 64 * j]; wB1[j] = p1[l + 64 * j]; }
    }
    const int orow = g * 8 + w;                   // my output row
    {
      const float4* p = (const float4*)(Wo + (size_t)orow * DH);
      #pragma unroll
      for (int j = 0; j < 8; ++j) wO[j] = p[l + 64 * j];
    }
    const float b1_0 = ba[r0] + bb[r0];
    const float b1_1 = ba[r1] + bb[r1];
    const float bo_r = bo[orow];

    for (int t = 1; t <= TT; ++t) {
      // A.x[t-1]: no cross-WG dependency — compute before the wait
      float a0 = 0.f, a1 = 0.f;
      {
        const float4* px = (const float4*)(X + (size_t)(t - 1) * DIN);
        #pragma unroll
        for (int j = 0; j < 4; ++j) {
          float4 x4 = px[l + 64 * j];
          a0 += dot4(wA0[j], x4);
          a1 += dot4(wA1[j], x4);
        }
      }
      if (t > 1) {
        float* buf = sA[(t - 1) & 1];
        poll_stage(gR1 + (size_t)(t - 1) * DH, buf, tid);
        __syncthreads();
        const float4* ph = (const float4*)buf;
        #pragma unroll
        for (int j = 0; j < 8; ++j) {
          float4 h4 = ph[l + 64 * j];
          a0 += dot4(wB0[j], h4);
          a1 += dot4(wB1[j], h4);
        }
      }
      a0 = wave_sum(a0); a1 = wave_sum(a1);
      if (l == 0) {   // publish: two fire-and-forget atomic u32 records
        u32* dst = gR1 + (size_t)t * DH;
        st_rec(dst + r0, __float_as_uint(fast_tanh(a0 + b1_0)));
        st_rec(dst + r1, __float_as_uint(fast_tanh(a1 + b1_1)));
      }
    }

    // ---- epilogue: out = Wo . h2[TT] + bo (1 row per wave) ----
    // Slow pre-gate on own first record so 128 WGs don't spin-pollute
    // phase 2; then the normal (brief) poll for the remaining records.
    {
      const u32* rec = gR2 + (size_t)TT * DH;
      while (ld_rec(rec + tid) == SENT) __builtin_amdgcn_s_sleep(64);
    }
    poll_stage(gR2 + (size_t)TT * DH, sA[0], tid);
    __syncthreads();
    {
      const float4* ph = (const float4*)sA[0];
      float acc = 0.f;
      #pragma unroll
      for (int j = 0; j < 8; ++j) acc += dot4(wO[j], ph[l + 64 * j]);
      acc = wave_sum(acc);
      if (l == 0) out[orow] = acc + bo_r;
    }
  } else {
    // ============ PHASE 2: h2 chain solo (h1 fully materialized) ============
    const int gg = g - HALF;
    const int r0 = gg * 16 + 2 * w, r1 = r0 + 1;  // my two h2 rows
    float4 wC0[8], wC1[8], wD0[8], wD1[8];
    {
      const float4* p0 = (const float4*)(Wc + (size_t)r0 * DH);
      const float4* p1 = (const float4*)(Wc + (size_t)r1 * DH);
      #pragma unroll
      for (int j = 0; j < 8; ++j) { wC0[j] = p0[l + 64 * j]; wC1[j] = p1[l + 64 * j]; }
    }
    {
      const float4* p0 = (const float4*)(Wd + (size_t)r0 * DH);
      const float4* p1 = (const float4*)(Wd + (size_t)r1 * DH);
      #pragma unroll
      for (int j = 0; j < 8; ++j) { wD0[j] = p0[l + 64 * j]; wD1[j] = p1[l + 64 * j]; }
    }
    const float b2_0 = bc[r0] + bd[r0];
    const float b2_1 = bc[r1] + bd[r1];

    // PHASE GATE: gR1[TT] complete => every h1 producer finished step TT =>
    // all h1 slots t=1..TT are fully published. Long-sleep poll keeps this
    // half of the device near-silent during phase 1.
    quiet_gate(gR1 + (size_t)TT * DH, tid);
    __syncthreads();

    for (int t = 1; t <= TT; ++t) {
      float* bufA = sA[t & 1];
      float* bufB = sB[t & 1];
      if (t > 1)
        poll_stage2(gR1 + (size_t)t * DH,
                    gR2 + (size_t)(t - 1) * DH, bufA, bufB, tid);
      else
        poll_stage(gR1 + (size_t)1 * DH, bufA, tid);
      __syncthreads();

      float a0 = 0.f, a1 = 0.f;
      {
        const float4* ph = (const float4*)bufA;
        #pragma unroll
        for (int j = 0; j < 8; ++j) {
          float4 h4 = ph[l + 64 * j];
          a0 += dot4(wC0[j], h4);
          a1 += dot4(wC1[j], h4);
        }
      }
      if (t > 1) {
        const float4* ph = (const float4*)bufB;
        #pragma unroll
        for (int j = 0; j < 8; ++j) {
          float4 h4 = ph[l + 64 * j];
          a0 += dot4(wD0[j], h4);
          a1 += dot4(wD1[j], h4);
        }
      }
      a0 = wave_sum(a0); a1 = wave_sum(a1);
      if (l == 0) {
        u32* dst = gR2 + (size_t)t * DH;
        st_rec(dst + r0, __float_as_uint(fast_tanh(a0 + b2_0)));
        st_rec(dst + r1, __float_as_uint(fast_tanh(a1 + b2_1)));
      }
    }
  }
}

extern "C" void kernel_launch(void* const* d_in, const int* in_sizes, int n_in,
                              void* d_out, int out_size, void* d_ws, size_t ws_size,
                              hipStream_t stream)
{
  (void)in_sizes; (void)n_in; (void)out_size; (void)d_ws; (void)ws_size;

  const float* X  = (const float*)d_in[0];
  const float* Wa = (const float*)d_in[1];   // W_i2h1 [H][IN]
  const float* ba = (const float*)d_in[2];
  const float* Wb = (const float*)d_in[3];   // W_h2h1 [H][H]
  const float* bb = (const float*)d_in[4];
  // d_in[5], d_in[6]: W_h2o1 / b_h2o1 — dead code in the reference
  const float* Wc = (const float*)d_in[7];   // W_i2h2 [H][H]
  const float* bc = (const float*)d_in[8];
  const float* Wd = (const float*)d_in[9];   // W_h2h2 [H][H]
  const float* bd = (const float*)d_in[10];
  const float* Wo = (const float*)d_in[11];  // W_h2o2 [OUT][H]
  const float* bo = (const float*)d_in[12];
  float* out = (float*)d_out;

  init_kernel<<<dim3(1024), dim3(256), 0, stream>>>();

  void* args[] = { &X, &Wa, &ba, &Wb, &bb, &Wc, &bc, &Wd, &bd, &Wo, &bo, &out };
  (void)hipLaunchCooperativeKernel((void*)rnn2_kernel, dim3(NWG), dim3(NTHR),
                                   args, 0, stream);
}

// Round 9
// 2967.187 us; speedup vs baseline: 1.9335x; 1.0120x over previous
//
#include <hip/hip_runtime.h>

// ---------------- problem dims ----------------
#define TT   512
#define DIN  1024
#define DH   2048
#define DOUT 1024

// ---------------- launch shape ----------------
#define NWG   256    // WGs 0..127: h1 chain (+epilogue); 128..255: h2 chain
#define HALF  128
#define NTHR  512    // 8 waves; each wave owns 2 h-rows of its chain
#define NSLOT (TT + 1)

typedef unsigned int u32;
typedef unsigned long long u64;

// Records: u32 = f32 bits of h; SENT (NaN pattern) = empty; tanh output can
// never be NaN -> data IS the readiness flag (one-RT observe, no fences).
// Slot-per-step -> no ABA. Sentinel re-init per run (8.4 MB).
//
// ROUND-8 CHANGE — PAIR-u64 POLLING (request-count cut, everything else
// R4-verbatim). Evidence chain: R1==R4 kills the byte model; R7 phase-split
// (solo period == joint period) kills cross-chain contention; R3/R5/R6
// (unconditional re-flood) all regress. Remaining suspect: L3-slice request
// queueing — each poll round sends ~2048 requests/WG at the slot's 128
// lines (16 threads per line per WG x 128 WGs intra-chain). This round each
// thread polls its 4 contiguous records as TWO back-to-back u64 loads
// (same 16B, HALF the requests: 1024/WG/round), checks batched after issue
// (sched_barrier keeps checks behind both loads -> one RT per round).
// Staging = one float4 per thread (R5-proven: 0 bank conflicts).
// Publish stays R4's immediate per-lane dual u32 store (aggregation was
// R5's +0.46us/step mistake). h1 additionally pre-issues round-0 loads
// before the independent X-dot (zero extra traffic, hides ~1 issue window).
#define SENT  0xFFFFFFFFu
__device__ u32 gR1[NSLOT * DH];   // h1 records
__device__ u32 gR2[NSLOT * DH];   // h2 records

__device__ __forceinline__ float dot4(float4 a, float4 b) {
  return a.x * b.x + a.y * b.y + a.z * b.z + a.w * b.w;
}
__device__ __forceinline__ float wave_sum(float v) {
  #pragma unroll
  for (int off = 32; off > 0; off >>= 1) v += __shfl_down(v, off, 64);
  return v; // lane 0 holds the sum
}
__device__ __forceinline__ u64 ld64(const u64* p) {
  return __hip_atomic_load((u64*)p, __ATOMIC_RELAXED, __HIP_MEMORY_SCOPE_AGENT);
}
__device__ __forceinline__ u32 ld_rec(const u32* p) {
  return __hip_atomic_load((u32*)p, __ATOMIC_RELAXED, __HIP_MEMORY_SCOPE_AGENT);
}
__device__ __forceinline__ void st_rec(u32* p, u32 v) {
  __hip_atomic_store(p, v, __ATOMIC_RELAXED, __HIP_MEMORY_SCOPE_AGENT);
}
// both u32 halves of a record-pair present? (bitwise &: no short-circuit)
__device__ __forceinline__ bool ok2(u64 q) {
  return ((u32)q != SENT) & ((u32)(q >> 32) != SENT);
}
// Fast tanh, ~3 ulp: lane 0 only, 2x per wave per step. Output always
// finite/non-NaN -> can never alias SENT.
__device__ __forceinline__ float fast_tanh(float x) {
  float xc = fminf(fmaxf(x, -9.0f), 9.0f);
  float e  = __expf(2.0f * xc);
  return (e - 1.0f) * __frcp_rn(e + 1.0f);
}
__device__ __forceinline__ void stage4(float* lds, int tid, u64 q0, u64 q1) {
  ((float4*)lds)[tid] = make_float4(
      __uint_as_float((u32)q0), __uint_as_float((u32)(q0 >> 32)),
      __uint_as_float((u32)q1), __uint_as_float((u32)(q1 >> 32)));
}

// Single-slot pair-poll: thread tid owns records 4tid..4tid+3 = u64 words
// {2tid, 2tid+1}. Two loads issue back-to-back, checks after the pair
// (sched_barrier fences) -> 1 RT/round, 1024 requests/WG/round.
__device__ __forceinline__ void poll_stage(const u32* rec, float* lds, int tid) {
  const u64* p = (const u64*)rec + 2 * (size_t)tid;
  u64 q0 = ld64(p), q1 = ld64(p + 1);
  __builtin_amdgcn_sched_barrier(0);
  while (!(ok2(q0) & ok2(q1))) {
    __builtin_amdgcn_s_sleep(1);
    q0 = ld64(p); q1 = ld64(p + 1);
    __builtin_amdgcn_sched_barrier(0);
  }
  stage4(lds, tid, q0, q1);
}

// Dual-slot pair-poll (h2 chain: h1[t] and h2[t-1]). Per-slot guards keep
// the finished slot's lanes quiet; all pending loads issue before any check.
__device__ __forceinline__ void poll_stage2(const u32* recA, const u32* recB,
                                            float* ldsA, float* ldsB, int tid) {
  const u64* pa = (const u64*)recA + 2 * (size_t)tid;
  const u64* pb = (const u64*)recB + 2 * (size_t)tid;
  u64 qa0 = ld64(pa), qa1 = ld64(pa + 1);
  u64 qb0 = ld64(pb), qb1 = ld64(pb + 1);
  __builtin_amdgcn_sched_barrier(0);
  bool da = ok2(qa0) & ok2(qa1);
  bool db = ok2(qb0) & ok2(qb1);
  while (!(da & db)) {
    __builtin_amdgcn_s_sleep(1);
    if (!da) { qa0 = ld64(pa); qa1 = ld64(pa + 1); }
    if (!db) { qb0 = ld64(pb); qb1 = ld64(pb + 1); }
    __builtin_amdgcn_sched_barrier(0);
    da = ok2(qa0) & ok2(qa1);
    db = ok2(qb0) & ok2(qb1);
  }
  stage4(ldsA, tid, qa0, qa1);
  stage4(ldsB, tid, qb0, qb1);
}

// Sentinel-fill all records before each run (agent-scope stores: must be
// visible to the main kernel's L2-bypassing poll loads).
__global__ void init_kernel() {
  int i = blockIdx.x * blockDim.x + threadIdx.x;
  int n = gridDim.x * blockDim.x;
  for (int k = i; k < NSLOT * DH; k += n) {
    st_rec(&gR1[k], SENT);
    st_rec(&gR2[k], SENT);
  }
}

__global__ __launch_bounds__(NTHR, 2)
void rnn2_kernel(const float* __restrict__ X,
                 const float* __restrict__ Wa, const float* __restrict__ ba,
                 const float* __restrict__ Wb, const float* __restrict__ bb,
                 const float* __restrict__ Wc, const float* __restrict__ bc,
                 const float* __restrict__ Wd, const float* __restrict__ bd,
                 const float* __restrict__ Wo, const float* __restrict__ bo,
                 float* __restrict__ out)
{
  const int g   = blockIdx.x;
  const int tid = threadIdx.x;
  const int w   = tid >> 6;   // wave
  const int l   = tid & 63;   // lane

  // Double-buffered staging; the one barrier per step between stage and dot
  // bounds wave skew -> parity-buffer reuse two steps later is race-free.
  __shared__ float sA[2][DH];
  __shared__ float sB[2][DH];

  if (g < HALF) {
    // ================= h1 chain (+ output epilogue) =================
    const int r0 = g * 16 + 2 * w, r1 = r0 + 1;   // my two h1 rows
    float4 wA0[4], wA1[4], wB0[8], wB1[8], wO[8];
    {
      const float4* p0 = (const float4*)(Wa + (size_t)r0 * DIN);
      const float4* p1 = (const float4*)(Wa + (size_t)r1 * DIN);
      #pragma unroll
      for (int j = 0; j < 4; ++j) { wA0[j] = p0[l + 64 * j]; wA1[j] = p1[l + 64 * j]; }
    }
    {
      const float4* p0 = (const float4*)(Wb + (size_t)r0 * DH);
      const float4* p1 = (const float4*)(Wb + (size_t)r1 * DH);
      #pragma unroll
      for (int j = 0; j < 8; ++j) { wB0[j] = p0[l + 64 * j]; wB1[j] = p1[l + 64 * j]; }
    }
    const int orow = g * 8 + w;                   // my output row
    {
      const float4* p = (const float4*)(Wo + (size_t)orow * DH);
      #pragma unroll
      for (int j = 0; j < 8; ++j) wO[j] = p[l + 64 * j];
    }
    const float b1_0 = ba[r0] + bb[r0];
    const float b1_1 = ba[r1] + bb[r1];
    const float bo_r = bo[orow];

    for (int t = 1; t <= TT; ++t) {
      // Pre-issue round 0 of the pair-poll (loads in flight during X-dot;
      // zero extra traffic — round 0 always loads everything anyway).
      const u64* pp = (const u64*)(gR1 + (size_t)(t - 1) * DH) + 2 * (size_t)tid;
      u64 q0 = 0, q1 = 0;
      if (t > 1) {
        q0 = ld64(pp); q1 = ld64(pp + 1);
        __builtin_amdgcn_sched_barrier(0);
      }

      // A.x[t-1]: no cross-WG dependency — compute before the wait
      float a0 = 0.f, a1 = 0.f;
      {
        const float4* px = (const float4*)(X + (size_t)(t - 1) * DIN);
        #pragma unroll
        for (int j = 0; j < 4; ++j) {
          float4 x4 = px[l + 64 * j];
          a0 += dot4(wA0[j], x4);
          a1 += dot4(wA1[j], x4);
        }
      }

      if (t > 1) {
        while (!(ok2(q0) & ok2(q1))) {
          __builtin_amdgcn_s_sleep(1);
          q0 = ld64(pp); q1 = ld64(pp + 1);
          __builtin_amdgcn_sched_barrier(0);
        }
        float* buf = sA[(t - 1) & 1];
        stage4(buf, tid, q0, q1);
        __syncthreads();
        const float4* ph = (const float4*)buf;
        #pragma unroll
        for (int j = 0; j < 8; ++j) {
          float4 h4 = ph[l + 64 * j];
          a0 += dot4(wB0[j], h4);
          a1 += dot4(wB1[j], h4);
        }
      }
      a0 = wave_sum(a0); a1 = wave_sum(a1);
      if (l == 0) {   // publish: two fire-and-forget atomic u32 records
        u32* dst = gR1 + (size_t)t * DH;
        st_rec(dst + r0, __float_as_uint(fast_tanh(a0 + b1_0)));
        st_rec(dst + r1, __float_as_uint(fast_tanh(a1 + b1_1)));
      }
    }

    // ---- epilogue: out = Wo . h2[TT] + bo (1 row per wave) ----
    // sA[0] parity != the loop's last dot buffer (sA[1]) -> race-free.
    poll_stage(gR2 + (size_t)TT * DH, sA[0], tid);
    __syncthreads();
    {
      const float4* ph = (const float4*)sA[0];
      float acc = 0.f;
      #pragma unroll
      for (int j = 0; j < 8; ++j) acc += dot4(wO[j], ph[l + 64 * j]);
      acc = wave_sum(acc);
      if (l == 0) out[orow] = acc + bo_r;
    }
  } else {
    // ========================= h2 chain =========================
    const int gg = g - HALF;
    const int r0 = gg * 16 + 2 * w, r1 = r0 + 1;  // my two h2 rows
    float4 wC0[8], wC1[8], wD0[8], wD1[8];
    {
      const float4* p0 = (const float4*)(Wc + (size_t)r0 * DH);
      const float4* p1 = (const float4*)(Wc + (size_t)r1 * DH);
      #pragma unroll
      for (int j = 0; j < 8; ++j) { wC0[j] = p0[l + 64 * j]; wC1[j] = p1[l + 64 * j]; }
    }
    {
      const float4* p0 = (const float4*)(Wd + (size_t)r0 * DH);
      const float4* p1 = (const float4*)(Wd + (size_t)r1 * DH);
      #pragma unroll
      for (int j = 0; j < 8; ++j) { wD0[j] = p0[l + 64 * j]; wD1[j] = p1[l + 64 * j]; }
    }
    const float b2_0 = bc[r0] + bd[r0];
    const float b2_1 = bc[r1] + bd[r1];

    for (int t = 1; t <= TT; ++t) {
      float* bufA = sA[t & 1];
      float* bufB = sB[t & 1];
      if (t > 1)
        poll_stage2(gR1 + (size_t)t * DH,
                    gR2 + (size_t)(t - 1) * DH, bufA, bufB, tid);
      else
        poll_stage(gR1 + (size_t)1 * DH, bufA, tid);
      __syncthreads();

      float a0 = 0.f, a1 = 0.f;
      {
        const float4* ph = (const float4*)bufA;
        #pragma unroll
        for (int j = 0; j < 8; ++j) {
          float4 h4 = ph[l + 64 * j];
          a0 += dot4(wC0[j], h4);
          a1 += dot4(wC1[j], h4);
        }
      }
      if (t > 1) {
        const float4* ph = (const float4*)bufB;
        #pragma unroll
        for (int j = 0; j < 8; ++j) {
          float4 h4 = ph[l + 64 * j];
          a0 += dot4(wD0[j], h4);
          a1 += dot4(wD1[j], h4);
        }
      }
      a0 = wave_sum(a0); a1 = wave_sum(a1);
      if (l == 0) {
        u32* dst = gR2 + (size_t)t * DH;
        st_rec(dst + r0, __float_as_uint(fast_tanh(a0 + b2_0)));
        st_rec(dst + r1, __float_as_uint(fast_tanh(a1 + b2_1)));
      }
    }
  }
}

extern "C" void kernel_launch(void* const* d_in, const int* in_sizes, int n_in,
                              void* d_out, int out_size, void* d_ws, size_t ws_size,
                              hipStream_t stream)
{
  (void)in_sizes; (void)n_in; (void)out_size; (void)d_ws; (void)ws_size;

  const float* X  = (const float*)d_in[0];
  const float* Wa = (const float*)d_in[1];   // W_i2h1 [H][IN]
  const float* ba = (const float*)d_in[2];
  const float* Wb = (const float*)d_in[3];   // W_h2h1 [H][H]
  const float* bb = (const float*)d_in[4];
  // d_in[5], d_in[6]: W_h2o1 / b_h2o1 — dead code in the reference
  const float* Wc = (const float*)d_in[7];   // W_i2h2 [H][H]
  const float* bc = (const float*)d_in[8];
  const float* Wd = (const float*)d_in[9];   // W_h2h2 [H][H]
  const float* bd = (const float*)d_in[10];
  const float* Wo = (const float*)d_in[11];  // W_h2o2 [OUT][H]
  const float* bo = (const float*)d_in[12];
  float* out = (float*)d_out;

  init_kernel<<<dim3(1024), dim3(256), 0, stream>>>();

  void* args[] = { &X, &Wa, &ba, &Wb, &bb, &Wc, &bc, &Wd, &bd, &Wo, &bo, &out };
  (void)hipLaunchCooperativeKernel((void*)rnn2_kernel, dim3(NWG), dim3(NTHR),
                                   args, 0, stream);
}